// Round 1
// baseline (4201.991 us; speedup 1.0000x reference)
//
#include <hip/hip_runtime.h>
#include <math.h>

#define NN 50000
#define EE 800000
#define EP (EE + NN)      // edges + self loops
#define BB 256
#define FF 128
#define HC 64             // H*C
#define NSLOPE 0.2f
#define EPSF 1e-5f

__device__ __forceinline__ void atomicMaxF(float* addr, float val) {
    if (val >= 0.0f) atomicMax((int*)addr, __float_as_int(val));
    else             atomicMin((unsigned int*)addr, __float_as_uint(val));
}

// ---------------- BatchNorm (eval) + zero cnt ----------------
__global__ void k_bn(const float* __restrict__ x, const float* __restrict__ g,
                     const float* __restrict__ bta, float* __restrict__ xn) {
    int i = blockIdx.x * blockDim.x + threadIdx.x;
    if (i >= NN * FF) return;
    int f = i & (FF - 1);
    xn[i] = x[i] * (1.0f / sqrtf(1.0f + EPSF)) * g[f] + bta[f];
}

__global__ void k_zero_cnt(float* __restrict__ cnt) {
    int i = threadIdx.x;
    if (i < BB) cnt[i] = 0.0f;
}

__global__ void k_count(const int* __restrict__ batch, float* __restrict__ cnt) {
    int i = blockIdx.x * blockDim.x + threadIdx.x;
    if (i < NN) atomicAdd(&cnt[batch[i]], 1.0f);
}

// ---------------- GEMM (h = in @ W) + attention scores ----------------
// block = 256 threads = 4 rows x 64 cols; wave (64 lanes) == one row
template <int FIN, int INSTRIDE>
__global__ void k_gemm_gat(const float* __restrict__ in, const float* __restrict__ W,
                           const float* __restrict__ a_s, const float* __restrict__ a_d,
                           float* __restrict__ h_lin, float* __restrict__ s_src,
                           float* __restrict__ s_dst) {
    __shared__ float Wl[FIN * HC];
    __shared__ float rows[4][FIN];
    int tid = threadIdx.x;
    int n0 = blockIdx.x * 4;
    for (int i = tid; i < FIN * HC; i += 256) Wl[i] = W[i];
    for (int i = tid; i < 4 * FIN; i += 256) {
        int r = i / FIN, k = i - r * FIN;
        int n = n0 + r;
        rows[r][k] = (n < NN) ? in[(long)n * INSTRIDE + k] : 0.0f;
    }
    __syncthreads();
    int r = tid >> 6, c = tid & 63;
    int n = n0 + r;
    float acc = 0.0f;
#pragma unroll
    for (int k = 0; k < FIN; ++k) acc += rows[r][k] * Wl[k * HC + c];
    if (n < NN) h_lin[(long)n * HC + c] = acc;
    // per-head score reduction: lanes [0,32) head 0, [32,64) head 1
    float ss = acc * a_s[c];
    float sd = acc * a_d[c];
#pragma unroll
    for (int msk = 16; msk >= 1; msk >>= 1) {
        ss += __shfl_xor(ss, msk);
        sd += __shfl_xor(sd, msk);
    }
    if (n < NN && (c & 31) == 0) {
        s_src[n * 2 + (c >> 5)] = ss;
        s_dst[n * 2 + (c >> 5)] = sd;
    }
}

// ---------------- per-layer init: bias into hcat slice, m=-inf, z=0 ----------
__global__ void k_init_layer(const float* __restrict__ bias, float* __restrict__ slice,
                             float* __restrict__ m, float* __restrict__ z) {
    int i = blockIdx.x * blockDim.x + threadIdx.x;
    if (i >= NN * HC) return;
    int n = i >> 6, c = i & 63;
    slice[(long)n * 192 + c] = bias[c];
    if (c < 2) { m[n * 2 + c] = -INFINITY; z[n * 2 + c] = 0.0f; }
}

// ---------------- edge pass A: segment max ----------------
__global__ void k_edge_max(const int* __restrict__ ei, const float* __restrict__ s_src,
                           const float* __restrict__ s_dst, float* __restrict__ m) {
    int e = blockIdx.x * blockDim.x + threadIdx.x;
    if (e >= EP) return;
    int s, d;
    if (e < EE) { s = ei[e]; d = ei[EE + e]; } else { s = e - EE; d = s; }
    float e0 = s_src[2 * s]     + s_dst[2 * d];
    float e1 = s_src[2 * s + 1] + s_dst[2 * d + 1];
    e0 = e0 > 0.0f ? e0 : NSLOPE * e0;
    e1 = e1 > 0.0f ? e1 : NSLOPE * e1;
    atomicMaxF(&m[2 * d], e0);
    atomicMaxF(&m[2 * d + 1], e1);
}

// ---------------- edge pass B: p = exp(e - m[dst]); z += p ----------------
__global__ void k_edge_sum(const int* __restrict__ ei, const float* __restrict__ s_src,
                           const float* __restrict__ s_dst, const float* __restrict__ m,
                           float* __restrict__ p_e, float* __restrict__ z) {
    int e = blockIdx.x * blockDim.x + threadIdx.x;
    if (e >= EP) return;
    int s, d;
    if (e < EE) { s = ei[e]; d = ei[EE + e]; } else { s = e - EE; d = s; }
    float e0 = s_src[2 * s]     + s_dst[2 * d];
    float e1 = s_src[2 * s + 1] + s_dst[2 * d + 1];
    e0 = e0 > 0.0f ? e0 : NSLOPE * e0;
    e1 = e1 > 0.0f ? e1 : NSLOPE * e1;
    float p0 = expf(e0 - m[2 * d]);
    float p1 = expf(e1 - m[2 * d + 1]);
    p_e[2 * e] = p0;
    p_e[2 * e + 1] = p1;
    atomicAdd(&z[2 * d], p0);
    atomicAdd(&z[2 * d + 1], p1);
}

// ---------------- edge pass C: scatter h[src]*w into hcat slice -------------
// one wave (64 lanes) per edge; lane = channel
__global__ void k_scatter(const int* __restrict__ ei, const float* __restrict__ p_e,
                          const float* __restrict__ z, const float* __restrict__ h_lin,
                          float* __restrict__ slice) {
    long t = (long)blockIdx.x * blockDim.x + threadIdx.x;
    long e = t >> 6;
    int lane = (int)(t & 63);
    if (e >= EP) return;
    int s, d;
    if (e < EE) { s = ei[e]; d = ei[EE + e]; } else { s = (int)(e - EE); d = s; }
    float p = p_e[2 * e + (lane >> 5)];
    float zz = z[2 * d + (lane >> 5)];
    float val = h_lin[(long)s * HC + lane] * (p / zz);
    atomicAdd(&slice[(long)d * 192 + lane], val);
}

// ---------------- elu in place on hcat slice ----------------
__global__ void k_elu(float* __restrict__ slice) {
    int i = blockIdx.x * blockDim.x + threadIdx.x;
    if (i >= NN * HC) return;
    int n = i >> 6, c = i & 63;
    float* p = &slice[(long)n * 192 + c];
    float v = *p;
    *p = v > 0.0f ? v : expm1f(v);
}

// ---------------- pool init ----------------
__global__ void k_pool_init(float* __restrict__ pmax, float* __restrict__ psum) {
    int i = blockIdx.x * blockDim.x + threadIdx.x;
    if (i < BB * 192) { pmax[i] = -INFINITY; psum[i] = 0.0f; }
}

// ---------------- LayerNorm(192) + segment max/sum pooling ----------------
// block = 256 = 4 nodes; wave == one node; lane covers 3 features (lane, +64, +128)
__global__ void k_ln_pool(const float* __restrict__ hcat, const int* __restrict__ batch,
                          const float* __restrict__ lng, const float* __restrict__ lnb,
                          float* __restrict__ pmax, float* __restrict__ psum) {
    int tid = threadIdx.x;
    int n = blockIdx.x * 4 + (tid >> 6);
    int lane = tid & 63;
    if (n >= NN) return;
    const float* row = hcat + (long)n * 192;
    float v0 = row[lane], v1 = row[64 + lane], v2 = row[128 + lane];
    float sum = v0 + v1 + v2;
    float sq  = v0 * v0 + v1 * v1 + v2 * v2;
#pragma unroll
    for (int msk = 32; msk >= 1; msk >>= 1) {
        sum += __shfl_xor(sum, msk);
        sq  += __shfl_xor(sq, msk);
    }
    float mu  = sum * (1.0f / 192.0f);
    float var = sq * (1.0f / 192.0f) - mu * mu;
    float inv = 1.0f / sqrtf(var + EPSF);
    int b = batch[n];
    float y0 = (v0 - mu) * inv * lng[lane]       + lnb[lane];
    float y1 = (v1 - mu) * inv * lng[64 + lane]  + lnb[64 + lane];
    float y2 = (v2 - mu) * inv * lng[128 + lane] + lnb[128 + lane];
    atomicMaxF(&pmax[b * 192 + lane], y0);        atomicAdd(&psum[b * 192 + lane], y0);
    atomicMaxF(&pmax[b * 192 + 64 + lane], y1);   atomicAdd(&psum[b * 192 + 64 + lane], y1);
    atomicMaxF(&pmax[b * 192 + 128 + lane], y2);  atomicAdd(&psum[b * 192 + 128 + lane], y2);
}

// ---------------- view projection: relu([max|mean] @ proj_W + b) ------------
__global__ void k_proj(const float* __restrict__ pmax, const float* __restrict__ psum,
                       const float* __restrict__ cnt, const float* __restrict__ pW,
                       const float* __restrict__ pb, float* __restrict__ view) {
    __shared__ float pooled[384];
    int b = blockIdx.x, tid = threadIdx.x; // 128 threads
    float invc = 1.0f / fmaxf(cnt[b], 1.0f);
    for (int i = tid; i < 384; i += 128)
        pooled[i] = (i < 192) ? pmax[b * 192 + i] : psum[b * 192 + (i - 192)] * invc;
    __syncthreads();
    float acc = pb[tid];
    for (int k = 0; k < 384; ++k) acc += pooled[k] * pW[k * 128 + tid];
    view[b * 128 + tid] = fmaxf(acc, 0.0f);
}

// ---------------- final gate + fuse + classifier ----------------
__global__ void k_final(const float* __restrict__ v0, const float* __restrict__ v1,
                        const float* __restrict__ v2,
                        const float* __restrict__ gW1, const float* __restrict__ gb1,
                        const float* __restrict__ gW2, const float* __restrict__ gb2,
                        const float* __restrict__ cW1, const float* __restrict__ cb1,
                        const float* __restrict__ cW2, const float* __restrict__ cb2,
                        const float* __restrict__ cW3, const float* __restrict__ cb3,
                        float* __restrict__ out) {
    __shared__ float gi[128], t1[64], alpha[3], fu[128], h1[128], h2[64];
    int b = blockIdx.x, tid = threadIdx.x; // 128 threads
    float a0 = v0[b * 128 + tid], a1 = v1[b * 128 + tid], a2 = v2[b * 128 + tid];
    gi[tid] = (a0 + a1 + a2) * (1.0f / 3.0f);
    __syncthreads();
    if (tid < 64) {
        float a = gb1[tid];
        for (int k = 0; k < 128; ++k) a += gi[k] * gW1[k * 64 + tid];
        t1[tid] = fmaxf(a, 0.0f);
    }
    __syncthreads();
    if (tid == 0) {
        float g[3];
        for (int j = 0; j < 3; ++j) {
            float a = gb2[j];
            for (int k = 0; k < 64; ++k) a += t1[k] * gW2[k * 3 + j];
            g[j] = a;
        }
        float mx = fmaxf(g[0], fmaxf(g[1], g[2]));
        float e0 = expf(g[0] - mx), e1 = expf(g[1] - mx), e2 = expf(g[2] - mx);
        float s = e0 + e1 + e2;
        alpha[0] = e0 / s; alpha[1] = e1 / s; alpha[2] = e2 / s;
    }
    __syncthreads();
    fu[tid] = alpha[0] * a0 + alpha[1] * a1 + alpha[2] * a2;
    __syncthreads();
    float a = cb1[tid];
    for (int k = 0; k < 128; ++k) a += fu[k] * cW1[k * 128 + tid];
    h1[tid] = fmaxf(a, 0.0f);
    __syncthreads();
    if (tid < 64) {
        float b2 = cb2[tid];
        for (int k = 0; k < 128; ++k) b2 += h1[k] * cW2[k * 64 + tid];
        h2[tid] = fmaxf(b2, 0.0f);
    }
    __syncthreads();
    if (tid == 0) {
        float a3 = cb3[0];
        for (int k = 0; k < 64; ++k) a3 += h2[k] * cW3[k];
        out[b] = a3;
    }
}

extern "C" void kernel_launch(void* const* d_in, const int* in_sizes, int n_in,
                              void* d_out, int out_size, void* d_ws, size_t ws_size,
                              hipStream_t stream) {
    const float* x     = (const float*)d_in[0];
    const int*   ei[3] = {(const int*)d_in[1], (const int*)d_in[2], (const int*)d_in[3]};
    const int*   batch = (const int*)d_in[4];
    const float* bn_g  = (const float*)d_in[5];
    const float* bn_b  = (const float*)d_in[6];
    const float *W[3][3], *As[3][3], *Ad[3][3], *Bi[3][3];
    for (int l = 0; l < 3; ++l) {
        const float* Wl  = (const float*)d_in[7 + 4 * l];
        const float* asl = (const float*)d_in[8 + 4 * l];
        const float* adl = (const float*)d_in[9 + 4 * l];
        const float* bl  = (const float*)d_in[10 + 4 * l];
        int fin = (l == 0) ? 128 : 64;
        for (int v = 0; v < 3; ++v) {
            W[v][l]  = Wl + (long)v * fin * HC;
            As[v][l] = asl + v * HC;
            Ad[v][l] = adl + v * HC;
            Bi[v][l] = bl + v * HC;
        }
    }
    const float* lng = (const float*)d_in[19];
    const float* lnb = (const float*)d_in[20];
    const float* pW  = (const float*)d_in[21];
    const float* pb  = (const float*)d_in[22];
    const float* gW1 = (const float*)d_in[23];
    const float* gb1 = (const float*)d_in[24];
    const float* gW2 = (const float*)d_in[25];
    const float* gb2 = (const float*)d_in[26];
    const float* cW1 = (const float*)d_in[27];
    const float* cb1 = (const float*)d_in[28];
    const float* cW2 = (const float*)d_in[29];
    const float* cb2 = (const float*)d_in[30];
    const float* cW3 = (const float*)d_in[31];
    const float* cb3 = (const float*)d_in[32];

    float* ws    = (float*)d_ws;
    float* xn    = ws;                        // N*128
    float* hcat  = xn + (long)NN * 128;       // N*192
    float* h_lin = hcat + (long)NN * 192;     // N*64
    float* s_src = h_lin + (long)NN * HC;     // N*2
    float* s_dst = s_src + NN * 2;            // N*2
    float* m     = s_dst + NN * 2;            // N*2
    float* z     = m + NN * 2;                // N*2
    float* p_e   = z + NN * 2;                // EP*2
    float* pmax  = p_e + (long)EP * 2;        // B*192
    float* psum  = pmax + BB * 192;           // B*192
    float* cnt   = psum + BB * 192;           // B
    float* views = cnt + BB;                  // 3*B*128

    k_bn<<<(NN * FF + 255) / 256, 256, 0, stream>>>(x, bn_g, bn_b, xn);
    k_zero_cnt<<<1, 256, 0, stream>>>(cnt);
    k_count<<<(NN + 255) / 256, 256, 0, stream>>>(batch, cnt);

    for (int v = 0; v < 3; ++v) {
        for (int l = 0; l < 3; ++l) {
            float* slice = hcat + l * HC;
            if (l == 0)
                k_gemm_gat<128, 128><<<(NN + 3) / 4, 256, 0, stream>>>(
                    xn, W[v][0], As[v][0], Ad[v][0], h_lin, s_src, s_dst);
            else
                k_gemm_gat<64, 192><<<(NN + 3) / 4, 256, 0, stream>>>(
                    hcat + (l - 1) * HC, W[v][l], As[v][l], Ad[v][l], h_lin, s_src, s_dst);
            k_init_layer<<<(NN * HC + 255) / 256, 256, 0, stream>>>(Bi[v][l], slice, m, z);
            k_edge_max<<<(EP + 255) / 256, 256, 0, stream>>>(ei[v], s_src, s_dst, m);
            k_edge_sum<<<(EP + 255) / 256, 256, 0, stream>>>(ei[v], s_src, s_dst, m, p_e, z);
            long tot = (long)EP * 64;
            k_scatter<<<(int)((tot + 255) / 256), 256, 0, stream>>>(ei[v], p_e, z, h_lin, slice);
            k_elu<<<(NN * HC + 255) / 256, 256, 0, stream>>>(slice);
        }
        k_pool_init<<<(BB * 192 + 255) / 256, 256, 0, stream>>>(pmax, psum);
        k_ln_pool<<<(NN + 3) / 4, 256, 0, stream>>>(hcat, batch, lng, lnb, pmax, psum);
        k_proj<<<BB, 128, 0, stream>>>(pmax, psum, cnt, pW, pb, views + (long)v * BB * 128);
    }
    k_final<<<BB, 128, 0, stream>>>(views, views + BB * 128, views + 2 * BB * 128,
                                    gW1, gb1, gW2, gb2, cW1, cb1, cW2, cb2, cW3, cb3,
                                    (float*)d_out);
}

// Round 2
// 1753.447 us; speedup vs baseline: 2.3964x; 2.3964x over previous
//
#include <hip/hip_runtime.h>
#include <math.h>

#define NN 50000
#define EE 800000
#define EP (EE + NN)      // edges + self loops
#define BB 256
#define FF 128
#define HC 64             // H*C
#define NSLOPE 0.2f
#define EPSF 1e-5f

__device__ __forceinline__ void atomicMaxF(float* addr, float val) {
    if (val >= 0.0f) atomicMax((int*)addr, __float_as_int(val));
    else             atomicMin((unsigned int*)addr, __float_as_uint(val));
}

// ---------------- BatchNorm (eval) ----------------
__global__ void k_bn(const float* __restrict__ x, const float* __restrict__ g,
                     const float* __restrict__ bta, float* __restrict__ xn) {
    int i = blockIdx.x * blockDim.x + threadIdx.x;
    if (i >= NN * FF) return;
    int f = i & (FF - 1);
    xn[i] = x[i] * (1.0f / sqrtf(1.0f + EPSF)) * g[f] + bta[f];
}

__global__ void k_zero_cnt(float* __restrict__ cnt) {
    int i = threadIdx.x;
    if (i < BB) cnt[i] = 0.0f;
}

__global__ void k_count(const int* __restrict__ batch, float* __restrict__ cnt) {
    int i = blockIdx.x * blockDim.x + threadIdx.x;
    if (i < NN) atomicAdd(&cnt[batch[i]], 1.0f);
}

// ================= CSR build (per view, sorted by dst) =================
__global__ void k_zero_deg(int* __restrict__ deg) {
    int i = blockIdx.x * blockDim.x + threadIdx.x;
    if (i < NN) deg[i] = 0;
}

__global__ void k_hist(const int* __restrict__ ei, int* __restrict__ deg) {
    int e = blockIdx.x * blockDim.x + threadIdx.x;
    if (e >= EP) return;
    int d = (e < EE) ? ei[EE + e] : (e - EE);
    atomicAdd(&deg[d], 1);
}

// block sums of deg (256 per block)
__global__ void k_scan1(const int* __restrict__ deg, int* __restrict__ bsum) {
    __shared__ int sh[256];
    int tid = threadIdx.x;
    int i = blockIdx.x * 256 + tid;
    int v = (i < NN) ? deg[i] : 0;
    sh[tid] = v;
    __syncthreads();
    for (int off = 128; off > 0; off >>= 1) {
        if (tid < off) sh[tid] += sh[tid + off];
        __syncthreads();
    }
    if (tid == 0) bsum[blockIdx.x] = sh[0];
}

// serial exclusive scan of block sums (nb ~ 196, negligible)
__global__ void k_scan2(int* __restrict__ bsum, int nb) {
    if (threadIdx.x == 0 && blockIdx.x == 0) {
        int run = 0;
        for (int k = 0; k < nb; ++k) { int t = bsum[k]; bsum[k] = run; run += t; }
    }
}

// per-block exclusive scan + offset -> rowptr, cur
__global__ void k_scan3(const int* __restrict__ deg, const int* __restrict__ bsum,
                        int* __restrict__ rowptr, int* __restrict__ cur) {
    __shared__ int sh[256];
    int tid = threadIdx.x;
    int i = blockIdx.x * 256 + tid;
    int v = (i < NN) ? deg[i] : 0;
    sh[tid] = v;
    __syncthreads();
    for (int off = 1; off < 256; off <<= 1) {
        int t = (tid >= off) ? sh[tid - off] : 0;
        __syncthreads();
        sh[tid] += t;
        __syncthreads();
    }
    if (i < NN) {
        int r = bsum[blockIdx.x] + sh[tid] - v;   // exclusive
        rowptr[i] = r;
        cur[i] = r;
    }
    if (i == 0) rowptr[NN] = EP;
}

__global__ void k_fill(const int* __restrict__ ei, int* __restrict__ cur,
                       int* __restrict__ col) {
    int e = blockIdx.x * blockDim.x + threadIdx.x;
    if (e >= EP) return;
    int s, d;
    if (e < EE) { s = ei[e]; d = ei[EE + e]; } else { s = e - EE; d = s; }
    int idx = atomicAdd(&cur[d], 1);
    col[idx] = s;
}

// ---------------- GEMM (h = in @ W) + attention scores ----------------
// block = 256 threads = 4 rows x 64 cols; wave (64 lanes) == one row
template <int FIN, int INSTRIDE>
__global__ void k_gemm_gat(const float* __restrict__ in, const float* __restrict__ W,
                           const float* __restrict__ a_s, const float* __restrict__ a_d,
                           float* __restrict__ h_lin, float* __restrict__ s_src,
                           float* __restrict__ s_dst) {
    __shared__ float Wl[FIN * HC];
    __shared__ float rows[4][FIN];
    int tid = threadIdx.x;
    int n0 = blockIdx.x * 4;
    for (int i = tid; i < FIN * HC; i += 256) Wl[i] = W[i];
    for (int i = tid; i < 4 * FIN; i += 256) {
        int r = i / FIN, k = i - r * FIN;
        int n = n0 + r;
        rows[r][k] = (n < NN) ? in[(long)n * INSTRIDE + k] : 0.0f;
    }
    __syncthreads();
    int r = tid >> 6, c = tid & 63;
    int n = n0 + r;
    float acc = 0.0f;
#pragma unroll
    for (int k = 0; k < FIN; ++k) acc += rows[r][k] * Wl[k * HC + c];
    if (n < NN) h_lin[(long)n * HC + c] = acc;
    float ss = acc * a_s[c];
    float sd = acc * a_d[c];
#pragma unroll
    for (int msk = 16; msk >= 1; msk >>= 1) {
        ss += __shfl_xor(ss, msk);
        sd += __shfl_xor(sd, msk);
    }
    if (n < NN && (c & 31) == 0) {
        s_src[n * 2 + (c >> 5)] = ss;
        s_dst[n * 2 + (c >> 5)] = sd;
    }
}

// ============ fused GAT aggregation: one wave per dst node ============
// online softmax over in-edges; lanes=edges for scores, lanes=channels for acc
__global__ void k_gat(const int* __restrict__ rowptr, const int* __restrict__ col,
                      const float* __restrict__ s_src, const float* __restrict__ s_dst,
                      const float* __restrict__ h_lin, const float* __restrict__ bias,
                      float* __restrict__ slice) {
    int wid = (int)(((long)blockIdx.x * blockDim.x + threadIdx.x) >> 6);
    int lane = threadIdx.x & 63;
    if (wid >= NN) return;
    int start = rowptr[wid], end = rowptr[wid + 1];
    float sd0 = s_dst[2 * wid], sd1 = s_dst[2 * wid + 1];
    float m0 = -INFINITY, m1 = -INFINITY, z0 = 0.0f, z1 = 0.0f, acc = 0.0f;
    for (int base = start; base < end; base += 64) {
        int i = base + lane;
        bool valid = i < end;
        int s = valid ? col[i] : 0;
        float e0 = -INFINITY, e1 = -INFINITY;
        if (valid) {
            float2 ss = *(const float2*)&s_src[2 * s];
            e0 = ss.x + sd0; e1 = ss.y + sd1;
            e0 = e0 > 0.0f ? e0 : NSLOPE * e0;
            e1 = e1 > 0.0f ? e1 : NSLOPE * e1;
        }
        float cm0 = e0, cm1 = e1;
#pragma unroll
        for (int msk = 32; msk >= 1; msk >>= 1) {
            cm0 = fmaxf(cm0, __shfl_xor(cm0, msk));
            cm1 = fmaxf(cm1, __shfl_xor(cm1, msk));
        }
        float nm0 = fmaxf(m0, cm0), nm1 = fmaxf(m1, cm1);
        float sc0 = (m0 == -INFINITY) ? 0.0f : expf(m0 - nm0);
        float sc1 = (m1 == -INFINITY) ? 0.0f : expf(m1 - nm1);
        float p0 = valid ? expf(e0 - nm0) : 0.0f;
        float p1 = valid ? expf(e1 - nm1) : 0.0f;
        float ps0 = p0, ps1 = p1;
#pragma unroll
        for (int msk = 32; msk >= 1; msk >>= 1) {
            ps0 += __shfl_xor(ps0, msk);
            ps1 += __shfl_xor(ps1, msk);
        }
        z0 = z0 * sc0 + ps0;
        z1 = z1 * sc1 + ps1;
        acc *= (lane < 32) ? sc0 : sc1;
        int cnt = min(64, end - base);
        for (int j = 0; j < cnt; ++j) {
            int sj = __shfl(s, j);
            float p0j = __shfl(p0, j);
            float p1j = __shfl(p1, j);
            float pw = (lane < 32) ? p0j : p1j;
            acc += h_lin[(long)sj * HC + lane] * pw;
        }
        m0 = nm0; m1 = nm1;
    }
    float w = acc / ((lane < 32) ? z0 : z1);
    float v = w + bias[lane];
    slice[(long)wid * 192 + lane] = v > 0.0f ? v : expm1f(v);
}

// ---------------- pool init ----------------
__global__ void k_pool_init(float* __restrict__ pmax, float* __restrict__ psum) {
    int i = blockIdx.x * blockDim.x + threadIdx.x;
    if (i < BB * 192) { pmax[i] = -INFINITY; psum[i] = 0.0f; }
}

// ---------------- LayerNorm(192) + segment max/sum pooling ----------------
__global__ void k_ln_pool(const float* __restrict__ hcat, const int* __restrict__ batch,
                          const float* __restrict__ lng, const float* __restrict__ lnb,
                          float* __restrict__ pmax, float* __restrict__ psum) {
    int tid = threadIdx.x;
    int n = blockIdx.x * 4 + (tid >> 6);
    int lane = tid & 63;
    if (n >= NN) return;
    const float* row = hcat + (long)n * 192;
    float v0 = row[lane], v1 = row[64 + lane], v2 = row[128 + lane];
    float sum = v0 + v1 + v2;
    float sq  = v0 * v0 + v1 * v1 + v2 * v2;
#pragma unroll
    for (int msk = 32; msk >= 1; msk >>= 1) {
        sum += __shfl_xor(sum, msk);
        sq  += __shfl_xor(sq, msk);
    }
    float mu  = sum * (1.0f / 192.0f);
    float var = sq * (1.0f / 192.0f) - mu * mu;
    float inv = 1.0f / sqrtf(var + EPSF);
    int b = batch[n];
    float y0 = (v0 - mu) * inv * lng[lane]       + lnb[lane];
    float y1 = (v1 - mu) * inv * lng[64 + lane]  + lnb[64 + lane];
    float y2 = (v2 - mu) * inv * lng[128 + lane] + lnb[128 + lane];
    atomicMaxF(&pmax[b * 192 + lane], y0);        atomicAdd(&psum[b * 192 + lane], y0);
    atomicMaxF(&pmax[b * 192 + 64 + lane], y1);   atomicAdd(&psum[b * 192 + 64 + lane], y1);
    atomicMaxF(&pmax[b * 192 + 128 + lane], y2);  atomicAdd(&psum[b * 192 + 128 + lane], y2);
}

// ---------------- view projection ----------------
__global__ void k_proj(const float* __restrict__ pmax, const float* __restrict__ psum,
                       const float* __restrict__ cnt, const float* __restrict__ pW,
                       const float* __restrict__ pb, float* __restrict__ view) {
    __shared__ float pooled[384];
    int b = blockIdx.x, tid = threadIdx.x; // 128 threads
    float invc = 1.0f / fmaxf(cnt[b], 1.0f);
    for (int i = tid; i < 384; i += 128)
        pooled[i] = (i < 192) ? pmax[b * 192 + i] : psum[b * 192 + (i - 192)] * invc;
    __syncthreads();
    float acc = pb[tid];
    for (int k = 0; k < 384; ++k) acc += pooled[k] * pW[k * 128 + tid];
    view[b * 128 + tid] = fmaxf(acc, 0.0f);
}

// ---------------- final gate + fuse + classifier ----------------
__global__ void k_final(const float* __restrict__ v0, const float* __restrict__ v1,
                        const float* __restrict__ v2,
                        const float* __restrict__ gW1, const float* __restrict__ gb1,
                        const float* __restrict__ gW2, const float* __restrict__ gb2,
                        const float* __restrict__ cW1, const float* __restrict__ cb1,
                        const float* __restrict__ cW2, const float* __restrict__ cb2,
                        const float* __restrict__ cW3, const float* __restrict__ cb3,
                        float* __restrict__ out) {
    __shared__ float gi[128], t1[64], alpha[3], fu[128], h1[128], h2[64];
    int b = blockIdx.x, tid = threadIdx.x; // 128 threads
    float a0 = v0[b * 128 + tid], a1 = v1[b * 128 + tid], a2 = v2[b * 128 + tid];
    gi[tid] = (a0 + a1 + a2) * (1.0f / 3.0f);
    __syncthreads();
    if (tid < 64) {
        float a = gb1[tid];
        for (int k = 0; k < 128; ++k) a += gi[k] * gW1[k * 64 + tid];
        t1[tid] = fmaxf(a, 0.0f);
    }
    __syncthreads();
    if (tid == 0) {
        float g[3];
        for (int j = 0; j < 3; ++j) {
            float a = gb2[j];
            for (int k = 0; k < 64; ++k) a += t1[k] * gW2[k * 3 + j];
            g[j] = a;
        }
        float mx = fmaxf(g[0], fmaxf(g[1], g[2]));
        float e0 = expf(g[0] - mx), e1 = expf(g[1] - mx), e2 = expf(g[2] - mx);
        float s = e0 + e1 + e2;
        alpha[0] = e0 / s; alpha[1] = e1 / s; alpha[2] = e2 / s;
    }
    __syncthreads();
    fu[tid] = alpha[0] * a0 + alpha[1] * a1 + alpha[2] * a2;
    __syncthreads();
    float a = cb1[tid];
    for (int k = 0; k < 128; ++k) a += fu[k] * cW1[k * 128 + tid];
    h1[tid] = fmaxf(a, 0.0f);
    __syncthreads();
    if (tid < 64) {
        float b2 = cb2[tid];
        for (int k = 0; k < 128; ++k) b2 += h1[k] * cW2[k * 64 + tid];
        h2[tid] = fmaxf(b2, 0.0f);
    }
    __syncthreads();
    if (tid == 0) {
        float a3 = cb3[0];
        for (int k = 0; k < 64; ++k) a3 += h2[k] * cW3[k];
        out[b] = a3;
    }
}

extern "C" void kernel_launch(void* const* d_in, const int* in_sizes, int n_in,
                              void* d_out, int out_size, void* d_ws, size_t ws_size,
                              hipStream_t stream) {
    const float* x     = (const float*)d_in[0];
    const int*   ei[3] = {(const int*)d_in[1], (const int*)d_in[2], (const int*)d_in[3]};
    const int*   batch = (const int*)d_in[4];
    const float* bn_g  = (const float*)d_in[5];
    const float* bn_b  = (const float*)d_in[6];
    const float *W[3][3], *As[3][3], *Ad[3][3], *Bi[3][3];
    for (int l = 0; l < 3; ++l) {
        const float* Wl  = (const float*)d_in[7 + 4 * l];
        const float* asl = (const float*)d_in[8 + 4 * l];
        const float* adl = (const float*)d_in[9 + 4 * l];
        const float* bl  = (const float*)d_in[10 + 4 * l];
        int fin = (l == 0) ? 128 : 64;
        for (int v = 0; v < 3; ++v) {
            W[v][l]  = Wl + (long)v * fin * HC;
            As[v][l] = asl + v * HC;
            Ad[v][l] = adl + v * HC;
            Bi[v][l] = bl + v * HC;
        }
    }
    const float* lng = (const float*)d_in[19];
    const float* lnb = (const float*)d_in[20];
    const float* pW  = (const float*)d_in[21];
    const float* pb  = (const float*)d_in[22];
    const float* gW1 = (const float*)d_in[23];
    const float* gb1 = (const float*)d_in[24];
    const float* gW2 = (const float*)d_in[25];
    const float* gb2 = (const float*)d_in[26];
    const float* cW1 = (const float*)d_in[27];
    const float* cb1 = (const float*)d_in[28];
    const float* cW2 = (const float*)d_in[29];
    const float* cb2 = (const float*)d_in[30];
    const float* cW3 = (const float*)d_in[31];
    const float* cb3 = (const float*)d_in[32];

    float* ws    = (float*)d_ws;
    float* xn    = ws;                        // N*128
    float* hcat  = xn + (long)NN * 128;       // N*192
    float* h_lin = hcat + (long)NN * 192;     // N*64
    float* s_src = h_lin + (long)NN * HC;     // N*2
    float* s_dst = s_src + NN * 2;            // N*2
    float* pmax  = s_dst + NN * 2;            // B*192
    float* psum  = pmax + BB * 192;           // B*192
    float* cnt   = psum + BB * 192;           // B
    float* views = cnt + BB;                  // 3*B*128
    int*   deg    = (int*)(views + 3 * BB * 128);  // N
    int*   rowptr = deg + NN;                 // N+1
    int*   cur    = rowptr + NN + 1;          // N
    int*   bsum   = cur + NN;                 // nb
    int*   col    = bsum + 256;               // EP

    const int NB = (NN + 255) / 256;          // 196 scan blocks

    k_bn<<<(NN * FF + 255) / 256, 256, 0, stream>>>(x, bn_g, bn_b, xn);
    k_zero_cnt<<<1, 256, 0, stream>>>(cnt);
    k_count<<<NB, 256, 0, stream>>>(batch, cnt);

    for (int v = 0; v < 3; ++v) {
        // ---- build CSR (dst-sorted, self loops included) ----
        k_zero_deg<<<NB, 256, 0, stream>>>(deg);
        k_hist<<<(EP + 255) / 256, 256, 0, stream>>>(ei[v], deg);
        k_scan1<<<NB, 256, 0, stream>>>(deg, bsum);
        k_scan2<<<1, 64, 0, stream>>>(bsum, NB);
        k_scan3<<<NB, 256, 0, stream>>>(deg, bsum, rowptr, cur);
        k_fill<<<(EP + 255) / 256, 256, 0, stream>>>(ei[v], cur, col);

        for (int l = 0; l < 3; ++l) {
            float* slice = hcat + l * HC;
            if (l == 0)
                k_gemm_gat<128, 128><<<(NN + 3) / 4, 256, 0, stream>>>(
                    xn, W[v][0], As[v][0], Ad[v][0], h_lin, s_src, s_dst);
            else
                k_gemm_gat<64, 192><<<(NN + 3) / 4, 256, 0, stream>>>(
                    hcat + (l - 1) * HC, W[v][l], As[v][l], Ad[v][l], h_lin, s_src, s_dst);
            k_gat<<<(NN + 3) / 4, 256, 0, stream>>>(rowptr, col, s_src, s_dst,
                                                    h_lin, Bi[v][l], slice);
        }
        k_pool_init<<<(BB * 192 + 255) / 256, 256, 0, stream>>>(pmax, psum);
        k_ln_pool<<<(NN + 3) / 4, 256, 0, stream>>>(hcat, batch, lng, lnb, pmax, psum);
        k_proj<<<BB, 128, 0, stream>>>(pmax, psum, cnt, pW, pb, views + (long)v * BB * 128);
    }
    k_final<<<BB, 128, 0, stream>>>(views, views + BB * 128, views + 2 * BB * 128,
                                    gW1, gb1, gW2, gb2, cW1, cb1, cW2, cb2, cW3, cb3,
                                    (float*)d_out);
}

// Round 3
// 1418.652 us; speedup vs baseline: 2.9620x; 1.2360x over previous
//
#include <hip/hip_runtime.h>
#include <math.h>

#define NN 50000
#define EE 800000
#define EP (EE + NN)      // edges + self loops
#define BB 256
#define FF 128
#define HC 64             // H*C
#define NSLOPE 0.2f
#define EPSF 1e-5f
#define PK 8              // pooling partials per batch

// ================= CSR build (per view, sorted by dst) =================
__global__ void k_zero_deg(int* __restrict__ deg) {
    int i = blockIdx.x * blockDim.x + threadIdx.x;
    if (i < NN) deg[i] = 0;
}

__global__ void k_hist(const int* __restrict__ ei, int* __restrict__ deg) {
    int e = blockIdx.x * blockDim.x + threadIdx.x;
    if (e >= EP) return;
    int d = (e < EE) ? ei[EE + e] : (e - EE);
    atomicAdd(&deg[d], 1);
}

__global__ void k_scan1(const int* __restrict__ deg, int* __restrict__ bsum) {
    __shared__ int sh[256];
    int tid = threadIdx.x;
    int i = blockIdx.x * 256 + tid;
    int v = (i < NN) ? deg[i] : 0;
    sh[tid] = v;
    __syncthreads();
    for (int off = 128; off > 0; off >>= 1) {
        if (tid < off) sh[tid] += sh[tid + off];
        __syncthreads();
    }
    if (tid == 0) bsum[blockIdx.x] = sh[0];
}

__global__ void k_scan2(int* __restrict__ bsum, int nb) {
    if (threadIdx.x == 0 && blockIdx.x == 0) {
        int run = 0;
        for (int k = 0; k < nb; ++k) { int t = bsum[k]; bsum[k] = run; run += t; }
    }
}

__global__ void k_scan3(const int* __restrict__ deg, const int* __restrict__ bsum,
                        int* __restrict__ rowptr, int* __restrict__ cur) {
    __shared__ int sh[256];
    int tid = threadIdx.x;
    int i = blockIdx.x * 256 + tid;
    int v = (i < NN) ? deg[i] : 0;
    sh[tid] = v;
    __syncthreads();
    for (int off = 1; off < 256; off <<= 1) {
        int t = (tid >= off) ? sh[tid - off] : 0;
        __syncthreads();
        sh[tid] += t;
        __syncthreads();
    }
    if (i < NN) {
        int r = bsum[blockIdx.x] + sh[tid] - v;
        rowptr[i] = r;
        cur[i] = r;
    }
    if (i == 0) rowptr[NN] = EP;
}

__global__ void k_fill(const int* __restrict__ ei, int* __restrict__ cur,
                       int* __restrict__ col) {
    int e = blockIdx.x * blockDim.x + threadIdx.x;
    if (e >= EP) return;
    int s, d;
    if (e < EE) { s = ei[e]; d = ei[EE + e]; } else { s = e - EE; d = s; }
    int idx = atomicAdd(&cur[d], 1);
    col[idx] = s;
}

// ---------------- batch segment boundaries (batch is sorted) ----------------
__global__ void k_bptr(const int* __restrict__ batch, int* __restrict__ bptr) {
    int n = blockIdx.x * blockDim.x + threadIdx.x;
    if (n >= NN) return;
    int b = batch[n];
    int prev = (n == 0) ? -1 : batch[n - 1];
    for (int q = prev + 1; q <= b; ++q) bptr[q] = n;
    if (n == NN - 1)
        for (int q = b + 1; q <= BB; ++q) bptr[q] = NN;
}

// ---------------- GEMM (h = in @ W) + attention scores ----------------
// block = 256 threads = 4 rows x 64 cols; wave (64 lanes) == one row
// BN=true folds eval-BatchNorm into the row load (layer 0 only).
template <int FIN, int INSTRIDE, bool BN>
__global__ void k_gemm_gat(const float* __restrict__ in, const float* __restrict__ W,
                           const float* __restrict__ a_s, const float* __restrict__ a_d,
                           const float* __restrict__ bn_g, const float* __restrict__ bn_b,
                           float* __restrict__ h_lin, float* __restrict__ s_src,
                           float* __restrict__ s_dst) {
    __shared__ float Wl[FIN * HC];
    __shared__ float rows[4][FIN];
    int tid = threadIdx.x;
    int n0 = blockIdx.x * 4;
    for (int i = tid; i < FIN * HC; i += 256) Wl[i] = W[i];
    const float rsq = 1.0f / sqrtf(1.0f + EPSF);
    for (int i = tid; i < 4 * FIN; i += 256) {
        int r = i / FIN, k = i - r * FIN;
        int n = n0 + r;
        float v = (n < NN) ? in[(long)n * INSTRIDE + k] : 0.0f;
        if (BN) v = v * (rsq * bn_g[k]) + bn_b[k];
        rows[r][k] = v;
    }
    __syncthreads();
    int r = tid >> 6, c = tid & 63;
    int n = n0 + r;
    float acc = 0.0f;
#pragma unroll
    for (int k = 0; k < FIN; ++k) acc += rows[r][k] * Wl[k * HC + c];
    if (n < NN) h_lin[(long)n * HC + c] = acc;
    float ss = acc * a_s[c];
    float sd = acc * a_d[c];
#pragma unroll
    for (int msk = 16; msk >= 1; msk >>= 1) {
        ss += __shfl_xor(ss, msk);
        sd += __shfl_xor(sd, msk);
    }
    if (n < NN && (c & 31) == 0) {
        s_src[n * 2 + (c >> 5)] = ss;
        s_dst[n * 2 + (c >> 5)] = sd;
    }
}

// ============ fused GAT aggregation: one wave per dst node ============
__global__ void k_gat(const int* __restrict__ rowptr, const int* __restrict__ col,
                      const float* __restrict__ s_src, const float* __restrict__ s_dst,
                      const float* __restrict__ h_lin, const float* __restrict__ bias,
                      float* __restrict__ slice) {
    int wid = (int)(((long)blockIdx.x * blockDim.x + threadIdx.x) >> 6);
    int lane = threadIdx.x & 63;
    if (wid >= NN) return;
    int start = rowptr[wid], end = rowptr[wid + 1];
    float sd0 = s_dst[2 * wid], sd1 = s_dst[2 * wid + 1];
    float m0 = -INFINITY, m1 = -INFINITY, z0 = 0.0f, z1 = 0.0f, acc = 0.0f;
    for (int base = start; base < end; base += 64) {
        int i = base + lane;
        bool valid = i < end;
        int s = valid ? col[i] : 0;
        float e0 = -INFINITY, e1 = -INFINITY;
        if (valid) {
            float2 ss = *(const float2*)&s_src[2 * s];
            e0 = ss.x + sd0; e1 = ss.y + sd1;
            e0 = e0 > 0.0f ? e0 : NSLOPE * e0;
            e1 = e1 > 0.0f ? e1 : NSLOPE * e1;
        }
        float cm0 = e0, cm1 = e1;
#pragma unroll
        for (int msk = 32; msk >= 1; msk >>= 1) {
            cm0 = fmaxf(cm0, __shfl_xor(cm0, msk));
            cm1 = fmaxf(cm1, __shfl_xor(cm1, msk));
        }
        float nm0 = fmaxf(m0, cm0), nm1 = fmaxf(m1, cm1);
        float sc0 = (m0 == -INFINITY) ? 0.0f : expf(m0 - nm0);
        float sc1 = (m1 == -INFINITY) ? 0.0f : expf(m1 - nm1);
        float p0 = valid ? expf(e0 - nm0) : 0.0f;
        float p1 = valid ? expf(e1 - nm1) : 0.0f;
        float ps0 = p0, ps1 = p1;
#pragma unroll
        for (int msk = 32; msk >= 1; msk >>= 1) {
            ps0 += __shfl_xor(ps0, msk);
            ps1 += __shfl_xor(ps1, msk);
        }
        z0 = z0 * sc0 + ps0;
        z1 = z1 * sc1 + ps1;
        acc *= (lane < 32) ? sc0 : sc1;
        int cnt = min(64, end - base);
        for (int j = 0; j < cnt; ++j) {
            int sj = __shfl(s, j);
            float p0j = __shfl(p0, j);
            float p1j = __shfl(p1, j);
            float pw = (lane < 32) ? p0j : p1j;
            acc += h_lin[(long)sj * HC + lane] * pw;
        }
        m0 = nm0; m1 = nm1;
    }
    float w = acc / ((lane < 32) ? z0 : z1);
    float v = w + bias[lane];
    slice[(long)wid * 192 + lane] = v > 0.0f ? v : expm1f(v);
}

// ---------------- LayerNorm stats: wave per node ----------------
__global__ void k_ln_stats(const float* __restrict__ hcat, float2* __restrict__ mu_inv) {
    int tid = threadIdx.x;
    int n = blockIdx.x * 4 + (tid >> 6);
    int lane = tid & 63;
    if (n >= NN) return;
    const float* row = hcat + (long)n * 192;
    float v0 = row[lane], v1 = row[64 + lane], v2 = row[128 + lane];
    float sum = v0 + v1 + v2;
    float sq  = v0 * v0 + v1 * v1 + v2 * v2;
#pragma unroll
    for (int msk = 32; msk >= 1; msk >>= 1) {
        sum += __shfl_xor(sum, msk);
        sq  += __shfl_xor(sq, msk);
    }
    if (lane == 0) {
        float mu  = sum * (1.0f / 192.0f);
        float var = sq * (1.0f / 192.0f) - mu * mu;
        mu_inv[n] = make_float2(mu, 1.0f / sqrtf(var + EPSF));
    }
}

// ---------------- pooling: grid B*PK, thread = feature, register reduce -----
__global__ void k_pool(const float* __restrict__ hcat, const int* __restrict__ bptr,
                       const float2* __restrict__ mu_inv, const float* __restrict__ lng,
                       const float* __restrict__ lnb, float* __restrict__ part) {
    int b  = blockIdx.x >> 3;
    int kk = blockIdx.x & (PK - 1);
    int f  = threadIdx.x;                 // 192 threads
    int s = bptr[b], e = bptr[b + 1];
    float g = lng[f], bo = lnb[f];
    float mx = -INFINITY, sm = 0.0f;
    for (int n = s + kk; n < e; n += PK) {
        float2 mi = mu_inv[n];
        float y = (hcat[(long)n * 192 + f] - mi.x) * mi.y * g + bo;
        mx = fmaxf(mx, y);
        sm += y;
    }
    long o = ((long)kk * BB + b) * 384;
    part[o + f] = mx;
    part[o + 192 + f] = sm;
}

// ---------------- view projection (folds PK partials) ----------------
__global__ void k_proj(const float* __restrict__ part, const int* __restrict__ bptr,
                       const float* __restrict__ pW, const float* __restrict__ pb,
                       float* __restrict__ view) {
    __shared__ float pooled[384];
    int b = blockIdx.x, tid = threadIdx.x;   // 128 threads
    float invc = 1.0f / fmaxf((float)(bptr[b + 1] - bptr[b]), 1.0f);
    for (int i = tid; i < 384; i += 128) {
        bool ismax = i < 192;
        float acc = ismax ? -INFINITY : 0.0f;
        for (int kk = 0; kk < PK; ++kk) {
            float v = part[((long)kk * BB + b) * 384 + i];
            acc = ismax ? fmaxf(acc, v) : (acc + v);
        }
        pooled[i] = ismax ? acc : acc * invc;
    }
    __syncthreads();
    float acc = pb[tid];
    for (int k = 0; k < 384; ++k) acc += pooled[k] * pW[k * 128 + tid];
    view[b * 128 + tid] = fmaxf(acc, 0.0f);
}

// ---------------- final gate + fuse + classifier ----------------
__global__ void k_final(const float* __restrict__ v0, const float* __restrict__ v1,
                        const float* __restrict__ v2,
                        const float* __restrict__ gW1, const float* __restrict__ gb1,
                        const float* __restrict__ gW2, const float* __restrict__ gb2,
                        const float* __restrict__ cW1, const float* __restrict__ cb1,
                        const float* __restrict__ cW2, const float* __restrict__ cb2,
                        const float* __restrict__ cW3, const float* __restrict__ cb3,
                        float* __restrict__ out) {
    __shared__ float gi[128], t1[64], alpha[3], fu[128], h1[128], h2[64];
    int b = blockIdx.x, tid = threadIdx.x;   // 128 threads
    float a0 = v0[b * 128 + tid], a1 = v1[b * 128 + tid], a2 = v2[b * 128 + tid];
    gi[tid] = (a0 + a1 + a2) * (1.0f / 3.0f);
    __syncthreads();
    if (tid < 64) {
        float a = gb1[tid];
        for (int k = 0; k < 128; ++k) a += gi[k] * gW1[k * 64 + tid];
        t1[tid] = fmaxf(a, 0.0f);
    }
    __syncthreads();
    if (tid == 0) {
        float g[3];
        for (int j = 0; j < 3; ++j) {
            float a = gb2[j];
            for (int k = 0; k < 64; ++k) a += t1[k] * gW2[k * 3 + j];
            g[j] = a;
        }
        float mx = fmaxf(g[0], fmaxf(g[1], g[2]));
        float e0 = expf(g[0] - mx), e1 = expf(g[1] - mx), e2 = expf(g[2] - mx);
        float s = e0 + e1 + e2;
        alpha[0] = e0 / s; alpha[1] = e1 / s; alpha[2] = e2 / s;
    }
    __syncthreads();
    fu[tid] = alpha[0] * a0 + alpha[1] * a1 + alpha[2] * a2;
    __syncthreads();
    float a = cb1[tid];
    for (int k = 0; k < 128; ++k) a += fu[k] * cW1[k * 128 + tid];
    h1[tid] = fmaxf(a, 0.0f);
    __syncthreads();
    if (tid < 64) {
        float b2 = cb2[tid];
        for (int k = 0; k < 128; ++k) b2 += h1[k] * cW2[k * 64 + tid];
        h2[tid] = fmaxf(b2, 0.0f);
    }
    __syncthreads();
    if (tid == 0) {
        float a3 = cb3[0];
        for (int k = 0; k < 64; ++k) a3 += h2[k] * cW3[k];
        out[b] = a3;
    }
}

extern "C" void kernel_launch(void* const* d_in, const int* in_sizes, int n_in,
                              void* d_out, int out_size, void* d_ws, size_t ws_size,
                              hipStream_t stream) {
    const float* x     = (const float*)d_in[0];
    const int*   ei[3] = {(const int*)d_in[1], (const int*)d_in[2], (const int*)d_in[3]};
    const int*   batch = (const int*)d_in[4];
    const float* bn_g  = (const float*)d_in[5];
    const float* bn_b  = (const float*)d_in[6];
    const float *W[3][3], *As[3][3], *Ad[3][3], *Bi[3][3];
    for (int l = 0; l < 3; ++l) {
        const float* Wl  = (const float*)d_in[7 + 4 * l];
        const float* asl = (const float*)d_in[8 + 4 * l];
        const float* adl = (const float*)d_in[9 + 4 * l];
        const float* bl  = (const float*)d_in[10 + 4 * l];
        int fin = (l == 0) ? 128 : 64;
        for (int v = 0; v < 3; ++v) {
            W[v][l]  = Wl + (long)v * fin * HC;
            As[v][l] = asl + v * HC;
            Ad[v][l] = adl + v * HC;
            Bi[v][l] = bl + v * HC;
        }
    }
    const float* lng = (const float*)d_in[19];
    const float* lnb = (const float*)d_in[20];
    const float* pW  = (const float*)d_in[21];
    const float* pb  = (const float*)d_in[22];
    const float* gW1 = (const float*)d_in[23];
    const float* gb1 = (const float*)d_in[24];
    const float* gW2 = (const float*)d_in[25];
    const float* gb2 = (const float*)d_in[26];
    const float* cW1 = (const float*)d_in[27];
    const float* cb1 = (const float*)d_in[28];
    const float* cW2 = (const float*)d_in[29];
    const float* cb2 = (const float*)d_in[30];
    const float* cW3 = (const float*)d_in[31];
    const float* cb3 = (const float*)d_in[32];

    float* ws     = (float*)d_ws;
    float* hcat   = ws;                         // N*192
    float* h_lin  = hcat + (long)NN * 192;      // N*64
    float* s_src  = h_lin + (long)NN * HC;      // N*2
    float* s_dst  = s_src + NN * 2;             // N*2
    float* mu_inv = s_dst + NN * 2;             // N*2 (float2[N])
    float* part   = mu_inv + NN * 2;            // PK*B*384
    float* views  = part + (long)PK * BB * 384; // 3*B*128
    int*   bptr   = (int*)(views + 3 * BB * 128);   // B+1
    int*   deg    = bptr + BB + 1;              // N
    int*   rowptr = deg + NN;                   // N+1
    int*   cur    = rowptr + NN + 1;            // N
    int*   bsum   = cur + NN;                   // 256
    int*   col    = bsum + 256;                 // EP

    const int NB = (NN + 255) / 256;

    k_bptr<<<NB, 256, 0, stream>>>(batch, bptr);

    for (int v = 0; v < 3; ++v) {
        // ---- build CSR (dst-sorted, self loops included) ----
        k_zero_deg<<<NB, 256, 0, stream>>>(deg);
        k_hist<<<(EP + 255) / 256, 256, 0, stream>>>(ei[v], deg);
        k_scan1<<<NB, 256, 0, stream>>>(deg, bsum);
        k_scan2<<<1, 64, 0, stream>>>(bsum, NB);
        k_scan3<<<NB, 256, 0, stream>>>(deg, bsum, rowptr, cur);
        k_fill<<<(EP + 255) / 256, 256, 0, stream>>>(ei[v], cur, col);

        for (int l = 0; l < 3; ++l) {
            float* slice = hcat + l * HC;
            if (l == 0)
                k_gemm_gat<128, 128, true><<<(NN + 3) / 4, 256, 0, stream>>>(
                    x, W[v][0], As[v][0], Ad[v][0], bn_g, bn_b, h_lin, s_src, s_dst);
            else
                k_gemm_gat<64, 192, false><<<(NN + 3) / 4, 256, 0, stream>>>(
                    hcat + (l - 1) * HC, W[v][l], As[v][l], Ad[v][l], bn_g, bn_b,
                    h_lin, s_src, s_dst);
            k_gat<<<(NN + 3) / 4, 256, 0, stream>>>(rowptr, col, s_src, s_dst,
                                                    h_lin, Bi[v][l], slice);
        }
        k_ln_stats<<<(NN + 3) / 4, 256, 0, stream>>>(hcat, (float2*)mu_inv);
        k_pool<<<BB * PK, 192, 0, stream>>>(hcat, bptr, (const float2*)mu_inv,
                                            lng, lnb, part);
        k_proj<<<BB, 128, 0, stream>>>(part, bptr, pW, pb, views + (long)v * BB * 128);
    }
    k_final<<<BB, 128, 0, stream>>>(views, views + BB * 128, views + 2 * BB * 128,
                                    gW1, gb1, gW2, gb2, cW1, cb1, cW2, cb2, cW3, cb3,
                                    (float*)d_out);
}

// Round 4
// 1072.093 us; speedup vs baseline: 3.9194x; 1.3233x over previous
//
#include <hip/hip_runtime.h>
#include <math.h>

#define NN 50000
#define EE 800000
#define EP (EE + NN)      // edges + self loops
#define BB 256
#define FF 128
#define HC 64             // H*C
#define NSLOPE 0.2f
#define EPSF 1e-5f
#define PK 8              // pooling partials per batch

// ================= CSR build (per view, sorted by dst) =================
__global__ void k_zero_deg(int* __restrict__ deg) {
    int i = blockIdx.x * blockDim.x + threadIdx.x;
    if (i < NN) deg[i] = 0;
}

__global__ void k_hist(const int* __restrict__ ei, int* __restrict__ deg) {
    int e = blockIdx.x * blockDim.x + threadIdx.x;
    if (e >= EP) return;
    int d = (e < EE) ? ei[EE + e] : (e - EE);
    atomicAdd(&deg[d], 1);
}

__global__ void k_scan1(const int* __restrict__ deg, int* __restrict__ bsum) {
    __shared__ int sh[256];
    int tid = threadIdx.x;
    int i = blockIdx.x * 256 + tid;
    int v = (i < NN) ? deg[i] : 0;
    sh[tid] = v;
    __syncthreads();
    for (int off = 128; off > 0; off >>= 1) {
        if (tid < off) sh[tid] += sh[tid + off];
        __syncthreads();
    }
    if (tid == 0) bsum[blockIdx.x] = sh[0];
}

__global__ void k_scan2(int* __restrict__ bsum, int nb) {
    if (threadIdx.x == 0 && blockIdx.x == 0) {
        int run = 0;
        for (int k = 0; k < nb; ++k) { int t = bsum[k]; bsum[k] = run; run += t; }
    }
}

__global__ void k_scan3(const int* __restrict__ deg, const int* __restrict__ bsum,
                        int* __restrict__ rowptr, int* __restrict__ cur) {
    __shared__ int sh[256];
    int tid = threadIdx.x;
    int i = blockIdx.x * 256 + tid;
    int v = (i < NN) ? deg[i] : 0;
    sh[tid] = v;
    __syncthreads();
    for (int off = 1; off < 256; off <<= 1) {
        int t = (tid >= off) ? sh[tid - off] : 0;
        __syncthreads();
        sh[tid] += t;
        __syncthreads();
    }
    if (i < NN) {
        int r = bsum[blockIdx.x] + sh[tid] - v;
        rowptr[i] = r;
        cur[i] = r;
    }
    if (i == 0) rowptr[NN] = EP;
}

__global__ void k_fill(const int* __restrict__ ei, int* __restrict__ cur,
                       int* __restrict__ col) {
    int e = blockIdx.x * blockDim.x + threadIdx.x;
    if (e >= EP) return;
    int s, d;
    if (e < EE) { s = ei[e]; d = ei[EE + e]; } else { s = e - EE; d = s; }
    int idx = atomicAdd(&cur[d], 1);
    col[idx] = s;
}

// ---------------- batch segment boundaries (batch is sorted) ----------------
__global__ void k_bptr(const int* __restrict__ batch, int* __restrict__ bptr) {
    int n = blockIdx.x * blockDim.x + threadIdx.x;
    if (n >= NN) return;
    int b = batch[n];
    int prev = (n == 0) ? -1 : batch[n - 1];
    for (int q = prev + 1; q <= b; ++q) bptr[q] = n;
    if (n == NN - 1)
        for (int q = b + 1; q <= BB; ++q) bptr[q] = NN;
}

// ---------------- GEMM (h = in @ W) + attention scores ----------------
// W column in registers (lane c holds W[:,c]); 32 rows staged in LDS per block;
// inner product reads rows via broadcast ds_read_b128. 4 waves x 8 rows each.
template <int FIN, int INSTRIDE, bool BN, int MINW>
__global__ __launch_bounds__(256, MINW)
void k_gemm_gat(const float* __restrict__ in, const float* __restrict__ W,
                const float* __restrict__ a_s, const float* __restrict__ a_d,
                const float* __restrict__ bn_g, const float* __restrict__ bn_b,
                float* __restrict__ h_lin, float* __restrict__ s_src,
                float* __restrict__ s_dst) {
    const int R = 8;
    __shared__ float rows[4 * R][FIN];
    int tid = threadIdx.x;
    int wv = tid >> 6, lane = tid & 63;
    int n0 = blockIdx.x * (4 * R);
    float wreg[FIN];
#pragma unroll
    for (int k = 0; k < FIN; ++k) wreg[k] = W[k * HC + lane];
    const float rsq = 1.0f / sqrtf(1.0f + EPSF);
    for (int i = tid; i < 4 * R * (FIN / 4); i += 256) {
        int r = i / (FIN / 4), k4 = (i % (FIN / 4)) * 4;
        int n = n0 + r;
        float4 v = make_float4(0.f, 0.f, 0.f, 0.f);
        if (n < NN) v = *(const float4*)&in[(long)n * INSTRIDE + k4];
        if (BN) {
            float4 g = *(const float4*)&bn_g[k4];
            float4 bo = *(const float4*)&bn_b[k4];
            v.x = v.x * rsq * g.x + bo.x;
            v.y = v.y * rsq * g.y + bo.y;
            v.z = v.z * rsq * g.z + bo.z;
            v.w = v.w * rsq * g.w + bo.w;
        }
        *(float4*)&rows[r][k4] = v;
    }
    __syncthreads();
    float as = a_s[lane], ad = a_d[lane];
    for (int rr = 0; rr < R; ++rr) {
        int r = wv * R + rr;
        int n = n0 + r;
        if (n >= NN) break;
        float acc = 0.0f;
#pragma unroll
        for (int k = 0; k < FIN; ++k) acc += rows[r][k] * wreg[k];
        h_lin[(long)n * HC + lane] = acc;
        float ss = acc * as, sd = acc * ad;
#pragma unroll
        for (int msk = 16; msk >= 1; msk >>= 1) {
            ss += __shfl_xor(ss, msk);
            sd += __shfl_xor(sd, msk);
        }
        if ((lane & 31) == 0) {
            s_src[n * 2 + (lane >> 5)] = ss;
            s_dst[n * 2 + (lane >> 5)] = sd;
        }
    }
}

// ============ fused GAT aggregation: one wave per dst node ============
// score phase: lane = edge (64-wide online softmax)
// aggregate phase: 4 edges/iter, 16 lanes per edge, lane owns 4 channels (float4)
__global__ void k_gat(const int* __restrict__ rowptr, const int* __restrict__ col,
                      const float* __restrict__ s_src, const float* __restrict__ s_dst,
                      const float* __restrict__ h_lin, const float* __restrict__ bias,
                      float* __restrict__ slice) {
    int wid = (int)(((long)blockIdx.x * blockDim.x + threadIdx.x) >> 6);
    int lane = threadIdx.x & 63;
    if (wid >= NN) return;
    int start = rowptr[wid], end = rowptr[wid + 1];
    float sd0 = s_dst[2 * wid], sd1 = s_dst[2 * wid + 1];
    int quarter = lane >> 4;
    int c4 = (lane & 15) << 2;
    bool hd1 = c4 >= 32;
    float m0 = -INFINITY, m1 = -INFINITY, z0 = 0.0f, z1 = 0.0f;
    float4 acc = make_float4(0.f, 0.f, 0.f, 0.f);
    for (int base = start; base < end; base += 64) {
        int i = base + lane;
        bool valid = i < end;
        int s = valid ? col[i] : 0;
        float e0 = -INFINITY, e1 = -INFINITY;
        if (valid) {
            float2 ss = *(const float2*)&s_src[2 * s];
            e0 = ss.x + sd0; e1 = ss.y + sd1;
            e0 = e0 > 0.0f ? e0 : NSLOPE * e0;
            e1 = e1 > 0.0f ? e1 : NSLOPE * e1;
        }
        float cm0 = e0, cm1 = e1;
#pragma unroll
        for (int msk = 32; msk >= 1; msk >>= 1) {
            cm0 = fmaxf(cm0, __shfl_xor(cm0, msk));
            cm1 = fmaxf(cm1, __shfl_xor(cm1, msk));
        }
        float nm0 = fmaxf(m0, cm0), nm1 = fmaxf(m1, cm1);
        float sc0 = (m0 == -INFINITY) ? 0.0f : expf(m0 - nm0);
        float sc1 = (m1 == -INFINITY) ? 0.0f : expf(m1 - nm1);
        float p0 = valid ? expf(e0 - nm0) : 0.0f;
        float p1 = valid ? expf(e1 - nm1) : 0.0f;
        float ps0 = p0, ps1 = p1;
#pragma unroll
        for (int msk = 32; msk >= 1; msk >>= 1) {
            ps0 += __shfl_xor(ps0, msk);
            ps1 += __shfl_xor(ps1, msk);
        }
        z0 = z0 * sc0 + ps0;
        z1 = z1 * sc1 + ps1;
        float sc = hd1 ? sc1 : sc0;
        acc.x *= sc; acc.y *= sc; acc.z *= sc; acc.w *= sc;
        int cnt = min(64, end - base);
        for (int j = 0; j < cnt; j += 4) {
            int jj = j + quarter;
            int sj = __shfl(s, jj);
            float p0j = __shfl(p0, jj);
            float p1j = __shfl(p1, jj);
            if (jj < cnt) {
                float pw = hd1 ? p1j : p0j;
                const float4 hv = *(const float4*)&h_lin[(long)sj * HC + c4];
                acc.x += hv.x * pw; acc.y += hv.y * pw;
                acc.z += hv.z * pw; acc.w += hv.w * pw;
            }
        }
        m0 = nm0; m1 = nm1;
    }
#pragma unroll
    for (int msk = 16; msk <= 32; msk <<= 1) {
        acc.x += __shfl_xor(acc.x, msk);
        acc.y += __shfl_xor(acc.y, msk);
        acc.z += __shfl_xor(acc.z, msk);
        acc.w += __shfl_xor(acc.w, msk);
    }
    if (lane < 16) {
        float zz = hd1 ? z1 : z0;
        float4 b4 = *(const float4*)&bias[c4];
        float4 o;
        o.x = acc.x / zz + b4.x;
        o.y = acc.y / zz + b4.y;
        o.z = acc.z / zz + b4.z;
        o.w = acc.w / zz + b4.w;
        o.x = o.x > 0.0f ? o.x : expm1f(o.x);
        o.y = o.y > 0.0f ? o.y : expm1f(o.y);
        o.z = o.z > 0.0f ? o.z : expm1f(o.z);
        o.w = o.w > 0.0f ? o.w : expm1f(o.w);
        *(float4*)&slice[(long)wid * 192 + c4] = o;
    }
}

// ---------------- LayerNorm stats: wave per node ----------------
__global__ void k_ln_stats(const float* __restrict__ hcat, float2* __restrict__ mu_inv) {
    int tid = threadIdx.x;
    int n = blockIdx.x * 4 + (tid >> 6);
    int lane = tid & 63;
    if (n >= NN) return;
    const float* row = hcat + (long)n * 192;
    float v0 = row[lane], v1 = row[64 + lane], v2 = row[128 + lane];
    float sum = v0 + v1 + v2;
    float sq  = v0 * v0 + v1 * v1 + v2 * v2;
#pragma unroll
    for (int msk = 32; msk >= 1; msk >>= 1) {
        sum += __shfl_xor(sum, msk);
        sq  += __shfl_xor(sq, msk);
    }
    if (lane == 0) {
        float mu  = sum * (1.0f / 192.0f);
        float var = sq * (1.0f / 192.0f) - mu * mu;
        mu_inv[n] = make_float2(mu, 1.0f / sqrtf(var + EPSF));
    }
}

// ---------------- pooling: grid B*PK, thread = feature, register reduce -----
__global__ void k_pool(const float* __restrict__ hcat, const int* __restrict__ bptr,
                       const float2* __restrict__ mu_inv, const float* __restrict__ lng,
                       const float* __restrict__ lnb, float* __restrict__ part) {
    int b  = blockIdx.x >> 3;
    int kk = blockIdx.x & (PK - 1);
    int f  = threadIdx.x;                 // 192 threads
    int s = bptr[b], e = bptr[b + 1];
    float g = lng[f], bo = lnb[f];
    float mx = -INFINITY, sm = 0.0f;
    for (int n = s + kk; n < e; n += PK) {
        float2 mi = mu_inv[n];
        float y = (hcat[(long)n * 192 + f] - mi.x) * mi.y * g + bo;
        mx = fmaxf(mx, y);
        sm += y;
    }
    long o = ((long)kk * BB + b) * 384;
    part[o + f] = mx;
    part[o + 192 + f] = sm;
}

// ---------------- view projection (folds PK partials) ----------------
__global__ void k_proj(const float* __restrict__ part, const int* __restrict__ bptr,
                       const float* __restrict__ pW, const float* __restrict__ pb,
                       float* __restrict__ view) {
    __shared__ float pooled[384];
    int b = blockIdx.x, tid = threadIdx.x;   // 128 threads
    float invc = 1.0f / fmaxf((float)(bptr[b + 1] - bptr[b]), 1.0f);
    for (int i = tid; i < 384; i += 128) {
        bool ismax = i < 192;
        float acc = ismax ? -INFINITY : 0.0f;
        for (int kk = 0; kk < PK; ++kk) {
            float v = part[((long)kk * BB + b) * 384 + i];
            acc = ismax ? fmaxf(acc, v) : (acc + v);
        }
        pooled[i] = ismax ? acc : acc * invc;
    }
    __syncthreads();
    float acc = pb[tid];
    for (int k = 0; k < 384; ++k) acc += pooled[k] * pW[k * 128 + tid];
    view[b * 128 + tid] = fmaxf(acc, 0.0f);
}

// ---------------- final gate + fuse + classifier ----------------
__global__ void k_final(const float* __restrict__ v0, const float* __restrict__ v1,
                        const float* __restrict__ v2,
                        const float* __restrict__ gW1, const float* __restrict__ gb1,
                        const float* __restrict__ gW2, const float* __restrict__ gb2,
                        const float* __restrict__ cW1, const float* __restrict__ cb1,
                        const float* __restrict__ cW2, const float* __restrict__ cb2,
                        const float* __restrict__ cW3, const float* __restrict__ cb3,
                        float* __restrict__ out) {
    __shared__ float gi[128], t1[64], alpha[3], fu[128], h1[128], h2[64];
    int b = blockIdx.x, tid = threadIdx.x;   // 128 threads
    float a0 = v0[b * 128 + tid], a1 = v1[b * 128 + tid], a2 = v2[b * 128 + tid];
    gi[tid] = (a0 + a1 + a2) * (1.0f / 3.0f);
    __syncthreads();
    if (tid < 64) {
        float a = gb1[tid];
        for (int k = 0; k < 128; ++k) a += gi[k] * gW1[k * 64 + tid];
        t1[tid] = fmaxf(a, 0.0f);
    }
    __syncthreads();
    if (tid == 0) {
        float g[3];
        for (int j = 0; j < 3; ++j) {
            float a = gb2[j];
            for (int k = 0; k < 64; ++k) a += t1[k] * gW2[k * 3 + j];
            g[j] = a;
        }
        float mx = fmaxf(g[0], fmaxf(g[1], g[2]));
        float e0 = expf(g[0] - mx), e1 = expf(g[1] - mx), e2 = expf(g[2] - mx);
        float s = e0 + e1 + e2;
        alpha[0] = e0 / s; alpha[1] = e1 / s; alpha[2] = e2 / s;
    }
    __syncthreads();
    fu[tid] = alpha[0] * a0 + alpha[1] * a1 + alpha[2] * a2;
    __syncthreads();
    float a = cb1[tid];
    for (int k = 0; k < 128; ++k) a += fu[k] * cW1[k * 128 + tid];
    h1[tid] = fmaxf(a, 0.0f);
    __syncthreads();
    if (tid < 64) {
        float b2 = cb2[tid];
        for (int k = 0; k < 128; ++k) b2 += h1[k] * cW2[k * 64 + tid];
        h2[tid] = fmaxf(b2, 0.0f);
    }
    __syncthreads();
    if (tid == 0) {
        float a3 = cb3[0];
        for (int k = 0; k < 64; ++k) a3 += h2[k] * cW3[k];
        out[b] = a3;
    }
}

extern "C" void kernel_launch(void* const* d_in, const int* in_sizes, int n_in,
                              void* d_out, int out_size, void* d_ws, size_t ws_size,
                              hipStream_t stream) {
    const float* x     = (const float*)d_in[0];
    const int*   ei[3] = {(const int*)d_in[1], (const int*)d_in[2], (const int*)d_in[3]};
    const int*   batch = (const int*)d_in[4];
    const float* bn_g  = (const float*)d_in[5];
    const float* bn_b  = (const float*)d_in[6];
    const float *W[3][3], *As[3][3], *Ad[3][3], *Bi[3][3];
    for (int l = 0; l < 3; ++l) {
        const float* Wl  = (const float*)d_in[7 + 4 * l];
        const float* asl = (const float*)d_in[8 + 4 * l];
        const float* adl = (const float*)d_in[9 + 4 * l];
        const float* bl  = (const float*)d_in[10 + 4 * l];
        int fin = (l == 0) ? 128 : 64;
        for (int v = 0; v < 3; ++v) {
            W[v][l]  = Wl + (long)v * fin * HC;
            As[v][l] = asl + v * HC;
            Ad[v][l] = adl + v * HC;
            Bi[v][l] = bl + v * HC;
        }
    }
    const float* lng = (const float*)d_in[19];
    const float* lnb = (const float*)d_in[20];
    const float* pW  = (const float*)d_in[21];
    const float* pb  = (const float*)d_in[22];
    const float* gW1 = (const float*)d_in[23];
    const float* gb1 = (const float*)d_in[24];
    const float* gW2 = (const float*)d_in[25];
    const float* gb2 = (const float*)d_in[26];
    const float* cW1 = (const float*)d_in[27];
    const float* cb1 = (const float*)d_in[28];
    const float* cW2 = (const float*)d_in[29];
    const float* cb2 = (const float*)d_in[30];
    const float* cW3 = (const float*)d_in[31];
    const float* cb3 = (const float*)d_in[32];

    float* ws     = (float*)d_ws;
    float* hcat   = ws;                         // N*192
    float* h_lin  = hcat + (long)NN * 192;      // N*64
    float* s_src  = h_lin + (long)NN * HC;      // N*2
    float* s_dst  = s_src + NN * 2;             // N*2
    float* mu_inv = s_dst + NN * 2;             // N*2 (float2[N])
    float* part   = mu_inv + NN * 2;            // PK*B*384
    float* views  = part + (long)PK * BB * 384; // 3*B*128
    int*   bptr   = (int*)(views + 3 * BB * 128);   // B+1
    int*   deg    = bptr + BB + 1;              // N
    int*   rowptr = deg + NN;                   // N+1
    int*   cur    = rowptr + NN + 1;            // N
    int*   bsum   = cur + NN;                   // 256
    int*   col    = bsum + 256;                 // EP

    const int NB = (NN + 255) / 256;

    k_bptr<<<NB, 256, 0, stream>>>(batch, bptr);

    for (int v = 0; v < 3; ++v) {
        // ---- build CSR (dst-sorted, self loops included) ----
        k_zero_deg<<<NB, 256, 0, stream>>>(deg);
        k_hist<<<(EP + 255) / 256, 256, 0, stream>>>(ei[v], deg);
        k_scan1<<<NB, 256, 0, stream>>>(deg, bsum);
        k_scan2<<<1, 64, 0, stream>>>(bsum, NB);
        k_scan3<<<NB, 256, 0, stream>>>(deg, bsum, rowptr, cur);
        k_fill<<<(EP + 255) / 256, 256, 0, stream>>>(ei[v], cur, col);

        for (int l = 0; l < 3; ++l) {
            float* slice = hcat + l * HC;
            if (l == 0)
                k_gemm_gat<128, 128, true, 2><<<(NN + 31) / 32, 256, 0, stream>>>(
                    x, W[v][0], As[v][0], Ad[v][0], bn_g, bn_b, h_lin, s_src, s_dst);
            else
                k_gemm_gat<64, 192, false, 4><<<(NN + 31) / 32, 256, 0, stream>>>(
                    hcat + (l - 1) * HC, W[v][l], As[v][l], Ad[v][l], bn_g, bn_b,
                    h_lin, s_src, s_dst);
            k_gat<<<(NN + 3) / 4, 256, 0, stream>>>(rowptr, col, s_src, s_dst,
                                                    h_lin, Bi[v][l], slice);
        }
        k_ln_stats<<<(NN + 3) / 4, 256, 0, stream>>>(hcat, (float2*)mu_inv);
        k_pool<<<BB * PK, 192, 0, stream>>>(hcat, bptr, (const float2*)mu_inv,
                                            lng, lnb, part);
        k_proj<<<BB, 128, 0, stream>>>(part, bptr, pW, pb, views + (long)v * BB * 128);
    }
    k_final<<<BB, 128, 0, stream>>>(views, views + BB * 128, views + 2 * BB * 128,
                                    gW1, gb1, gW2, gb2, cW1, cb1, cW2, cb2, cW3, cb3,
                                    (float*)d_out);
}

// Round 5
// 1036.153 us; speedup vs baseline: 4.0554x; 1.0347x over previous
//
#include <hip/hip_runtime.h>
#include <math.h>

#define NN 50000
#define EE 800000
#define EP (EE + NN)      // edges + self loops
#define BB 256
#define FF 128
#define HC 64             // H*C
#define NSLOPE 0.2f
#define EPSF 1e-5f
#define PK 8              // pooling partials per batch

// ================= CSR build: batched across 3 views (blockIdx.y = view) ====
__global__ void k_hist3(const int* __restrict__ e0, const int* __restrict__ e1,
                        const int* __restrict__ e2, int* __restrict__ deg) {
    int e = blockIdx.x * blockDim.x + threadIdx.x;
    if (e >= EP) return;
    int v = blockIdx.y;
    const int* ei = (v == 0) ? e0 : (v == 1) ? e1 : e2;
    int d = (e < EE) ? ei[EE + e] : (e - EE);
    atomicAdd(&deg[v * NN + d], 1);
}

__global__ void k_scan1(const int* __restrict__ deg, int* __restrict__ bsum) {
    __shared__ int sh[256];
    int tid = threadIdx.x;
    int i = blockIdx.x * 256 + tid;
    int v = (i < NN) ? deg[blockIdx.y * NN + i] : 0;
    sh[tid] = v;
    __syncthreads();
    for (int off = 128; off > 0; off >>= 1) {
        if (tid < off) sh[tid] += sh[tid + off];
        __syncthreads();
    }
    if (tid == 0) bsum[blockIdx.y * 256 + blockIdx.x] = sh[0];
}

__global__ void k_scan2(int* __restrict__ bsum, int nb) {
    if (threadIdx.x == 0) {
        int* bs = bsum + blockIdx.x * 256;
        int run = 0;
        for (int k = 0; k < nb; ++k) { int t = bs[k]; bs[k] = run; run += t; }
    }
}

__global__ void k_scan3(const int* __restrict__ deg, const int* __restrict__ bsum,
                        int* __restrict__ rowptr, int* __restrict__ cur) {
    __shared__ int sh[256];
    int tid = threadIdx.x;
    int vb = blockIdx.y;
    int i = blockIdx.x * 256 + tid;
    int v = (i < NN) ? deg[vb * NN + i] : 0;
    sh[tid] = v;
    __syncthreads();
    for (int off = 1; off < 256; off <<= 1) {
        int t = (tid >= off) ? sh[tid - off] : 0;
        __syncthreads();
        sh[tid] += t;
        __syncthreads();
    }
    if (i < NN) {
        int r = bsum[vb * 256 + blockIdx.x] + sh[tid] - v;
        rowptr[vb * (NN + 1) + i] = r;
        cur[vb * NN + i] = r;
    }
    if (i == 0) rowptr[vb * (NN + 1) + NN] = EP;
}

__global__ void k_fill3(const int* __restrict__ e0, const int* __restrict__ e1,
                        const int* __restrict__ e2, int* __restrict__ cur,
                        int* __restrict__ col) {
    int e = blockIdx.x * blockDim.x + threadIdx.x;
    if (e >= EP) return;
    int v = blockIdx.y;
    const int* ei = (v == 0) ? e0 : (v == 1) ? e1 : e2;
    int s, d;
    if (e < EE) { s = ei[e]; d = ei[EE + e]; } else { s = e - EE; d = s; }
    int idx = atomicAdd(&cur[v * NN + d], 1);
    col[(long)v * EP + idx] = s;
}

// ---------------- batch segment boundaries (batch is sorted) ----------------
__global__ void k_bptr(const int* __restrict__ batch, int* __restrict__ bptr) {
    int n = blockIdx.x * blockDim.x + threadIdx.x;
    if (n >= NN) return;
    int b = batch[n];
    int prev = (n == 0) ? -1 : batch[n - 1];
    for (int q = prev + 1; q <= b; ++q) bptr[q] = n;
    if (n == NN - 1)
        for (int q = b + 1; q <= BB; ++q) bptr[q] = NN;
}

// ---------------- GEMM (h = in @ W) + attention scores ----------------
// W column in registers (lane c holds W[:,c]); 32 rows staged in LDS per block.
template <int FIN, int INSTRIDE, bool BN, int MINW>
__global__ __launch_bounds__(256, MINW)
void k_gemm_gat(const float* __restrict__ in, const float* __restrict__ W,
                const float* __restrict__ a_s, const float* __restrict__ a_d,
                const float* __restrict__ bn_g, const float* __restrict__ bn_b,
                float* __restrict__ h_lin, float* __restrict__ s_src,
                float* __restrict__ s_dst) {
    const int R = 8;
    __shared__ float rows[4 * R][FIN];
    int tid = threadIdx.x;
    int wv = tid >> 6, lane = tid & 63;
    int n0 = blockIdx.x * (4 * R);
    float wreg[FIN];
#pragma unroll
    for (int k = 0; k < FIN; ++k) wreg[k] = W[k * HC + lane];
    const float rsq = 1.0f / sqrtf(1.0f + EPSF);
    for (int i = tid; i < 4 * R * (FIN / 4); i += 256) {
        int r = i / (FIN / 4), k4 = (i % (FIN / 4)) * 4;
        int n = n0 + r;
        float4 v = make_float4(0.f, 0.f, 0.f, 0.f);
        if (n < NN) v = *(const float4*)&in[(long)n * INSTRIDE + k4];
        if (BN) {
            float4 g = *(const float4*)&bn_g[k4];
            float4 bo = *(const float4*)&bn_b[k4];
            v.x = v.x * rsq * g.x + bo.x;
            v.y = v.y * rsq * g.y + bo.y;
            v.z = v.z * rsq * g.z + bo.z;
            v.w = v.w * rsq * g.w + bo.w;
        }
        *(float4*)&rows[r][k4] = v;
    }
    __syncthreads();
    float as = a_s[lane], ad = a_d[lane];
    for (int rr = 0; rr < R; ++rr) {
        int r = wv * R + rr;
        int n = n0 + r;
        if (n >= NN) break;
        float acc = 0.0f;
#pragma unroll
        for (int k = 0; k < FIN; ++k) acc += rows[r][k] * wreg[k];
        h_lin[(long)n * HC + lane] = acc;
        float ss = acc * as, sd = acc * ad;
#pragma unroll
        for (int msk = 16; msk >= 1; msk >>= 1) {
            ss += __shfl_xor(ss, msk);
            sd += __shfl_xor(sd, msk);
        }
        if ((lane & 31) == 0) {
            s_src[n * 2 + (lane >> 5)] = ss;
            s_dst[n * 2 + (lane >> 5)] = sd;
        }
    }
}

// ============ fused GAT aggregation: one 16-lane group per dst node ==========
// 4 nodes per wave. Score phase: lane = edge (16-wide online softmax).
// Aggregate: serial over chunk edges, lane owns 4 channels (float4 row loads).
__global__ void k_gat(const int* __restrict__ rowptr, const int* __restrict__ col,
                      const float* __restrict__ s_src, const float* __restrict__ s_dst,
                      const float* __restrict__ h_lin, const float* __restrict__ bias,
                      float* __restrict__ slice) {
    int tid = threadIdx.x;
    int wid = blockIdx.x * 16 + (tid >> 4);     // node
    int l16 = tid & 15;                          // lane in group
    int gbase = (tid & 63) & ~15;                // group's first lane in wave
    if (wid >= NN) return;
    int start = rowptr[wid], end = rowptr[wid + 1];
    float sd0 = s_dst[2 * wid], sd1 = s_dst[2 * wid + 1];
    int c4 = l16 << 2;
    bool hd1 = c4 >= 32;
    float m0 = -INFINITY, m1 = -INFINITY, z0 = 0.0f, z1 = 0.0f;
    float4 acc = make_float4(0.f, 0.f, 0.f, 0.f);
    for (int base = start; base < end; base += 16) {
        int i = base + l16;
        bool valid = i < end;
        int s = valid ? col[i] : 0;
        float e0 = -INFINITY, e1 = -INFINITY;
        if (valid) {
            float2 ss = *(const float2*)&s_src[2 * s];
            e0 = ss.x + sd0; e1 = ss.y + sd1;
            e0 = e0 > 0.0f ? e0 : NSLOPE * e0;
            e1 = e1 > 0.0f ? e1 : NSLOPE * e1;
        }
        float cm0 = e0, cm1 = e1;
#pragma unroll
        for (int msk = 8; msk >= 1; msk >>= 1) {
            cm0 = fmaxf(cm0, __shfl_xor(cm0, msk));
            cm1 = fmaxf(cm1, __shfl_xor(cm1, msk));
        }
        float nm0 = fmaxf(m0, cm0), nm1 = fmaxf(m1, cm1);
        float sc0 = (m0 == -INFINITY) ? 0.0f : __expf(m0 - nm0);
        float sc1 = (m1 == -INFINITY) ? 0.0f : __expf(m1 - nm1);
        float p0 = valid ? __expf(e0 - nm0) : 0.0f;
        float p1 = valid ? __expf(e1 - nm1) : 0.0f;
        float ps0 = p0, ps1 = p1;
#pragma unroll
        for (int msk = 8; msk >= 1; msk >>= 1) {
            ps0 += __shfl_xor(ps0, msk);
            ps1 += __shfl_xor(ps1, msk);
        }
        z0 = z0 * sc0 + ps0;
        z1 = z1 * sc1 + ps1;
        float sc = hd1 ? sc1 : sc0;
        acc.x *= sc; acc.y *= sc; acc.z *= sc; acc.w *= sc;
        int cnt = min(16, end - base);
        for (int j = 0; j < cnt; ++j) {
            int sj = __shfl(s, gbase + j);
            float p0j = __shfl(p0, gbase + j);
            float p1j = __shfl(p1, gbase + j);
            float pw = hd1 ? p1j : p0j;
            const float4 hv = *(const float4*)&h_lin[(long)sj * HC + c4];
            acc.x += hv.x * pw; acc.y += hv.y * pw;
            acc.z += hv.z * pw; acc.w += hv.w * pw;
        }
        m0 = nm0; m1 = nm1;
    }
    float zz = hd1 ? z1 : z0;
    float4 b4 = *(const float4*)&bias[c4];
    float4 o;
    o.x = acc.x / zz + b4.x;
    o.y = acc.y / zz + b4.y;
    o.z = acc.z / zz + b4.z;
    o.w = acc.w / zz + b4.w;
    o.x = o.x > 0.0f ? o.x : __expf(o.x) - 1.0f;
    o.y = o.y > 0.0f ? o.y : __expf(o.y) - 1.0f;
    o.z = o.z > 0.0f ? o.z : __expf(o.z) - 1.0f;
    o.w = o.w > 0.0f ? o.w : __expf(o.w) - 1.0f;
    *(float4*)&slice[(long)wid * 192 + c4] = o;
}

// ------ fused LayerNorm + pooling: grid B*PK, 192 threads (f = feature) -----
__global__ void k_pool(const float* __restrict__ hcat, const int* __restrict__ bptr,
                       const float* __restrict__ lng, const float* __restrict__ lnb,
                       float* __restrict__ part) {
    __shared__ float ssum[3], ssq[3];
    int b  = blockIdx.x >> 3;
    int kk = blockIdx.x & (PK - 1);
    int f  = threadIdx.x;                 // 192 threads
    int wv = f >> 6, lane = f & 63;
    int s = bptr[b], e = bptr[b + 1];
    float g = lng[f], bo = lnb[f];
    float mx = -INFINITY, sm = 0.0f;
    for (int n = s + kk; n < e; n += PK) {
        float v = hcat[(long)n * 192 + f];
        float sum = v, sq = v * v;
#pragma unroll
        for (int msk = 32; msk >= 1; msk >>= 1) {
            sum += __shfl_xor(sum, msk);
            sq  += __shfl_xor(sq, msk);
        }
        if (lane == 0) { ssum[wv] = sum; ssq[wv] = sq; }
        __syncthreads();
        float tot  = ssum[0] + ssum[1] + ssum[2];
        float totq = ssq[0] + ssq[1] + ssq[2];
        __syncthreads();
        float mu  = tot * (1.0f / 192.0f);
        float var = totq * (1.0f / 192.0f) - mu * mu;
        float inv = 1.0f / sqrtf(var + EPSF);
        float y = (v - mu) * inv * g + bo;
        mx = fmaxf(mx, y);
        sm += y;
    }
    long o = ((long)kk * BB + b) * 384;
    part[o + f] = mx;
    part[o + 192 + f] = sm;
}

// ---------------- view projection (folds PK partials) ----------------
__global__ void k_proj(const float* __restrict__ part, const int* __restrict__ bptr,
                       const float* __restrict__ pW, const float* __restrict__ pb,
                       float* __restrict__ view) {
    __shared__ float pooled[384];
    int b = blockIdx.x, tid = threadIdx.x;   // 128 threads
    float invc = 1.0f / fmaxf((float)(bptr[b + 1] - bptr[b]), 1.0f);
    for (int i = tid; i < 384; i += 128) {
        bool ismax = i < 192;
        float acc = ismax ? -INFINITY : 0.0f;
        for (int kk = 0; kk < PK; ++kk) {
            float v = part[((long)kk * BB + b) * 384 + i];
            acc = ismax ? fmaxf(acc, v) : (acc + v);
        }
        pooled[i] = ismax ? acc : acc * invc;
    }
    __syncthreads();
    float acc = pb[tid];
    for (int k = 0; k < 384; ++k) acc += pooled[k] * pW[k * 128 + tid];
    view[b * 128 + tid] = fmaxf(acc, 0.0f);
}

// ---------------- final gate + fuse + classifier ----------------
__global__ void k_final(const float* __restrict__ v0, const float* __restrict__ v1,
                        const float* __restrict__ v2,
                        const float* __restrict__ gW1, const float* __restrict__ gb1,
                        const float* __restrict__ gW2, const float* __restrict__ gb2,
                        const float* __restrict__ cW1, const float* __restrict__ cb1,
                        const float* __restrict__ cW2, const float* __restrict__ cb2,
                        const float* __restrict__ cW3, const float* __restrict__ cb3,
                        float* __restrict__ out) {
    __shared__ float gi[128], t1[64], alpha[3], fu[128], h1[128], h2[64];
    int b = blockIdx.x, tid = threadIdx.x;   // 128 threads
    float a0 = v0[b * 128 + tid], a1 = v1[b * 128 + tid], a2 = v2[b * 128 + tid];
    gi[tid] = (a0 + a1 + a2) * (1.0f / 3.0f);
    __syncthreads();
    if (tid < 64) {
        float a = gb1[tid];
        for (int k = 0; k < 128; ++k) a += gi[k] * gW1[k * 64 + tid];
        t1[tid] = fmaxf(a, 0.0f);
    }
    __syncthreads();
    if (tid == 0) {
        float g[3];
        for (int j = 0; j < 3; ++j) {
            float a = gb2[j];
            for (int k = 0; k < 64; ++k) a += t1[k] * gW2[k * 3 + j];
            g[j] = a;
        }
        float mx = fmaxf(g[0], fmaxf(g[1], g[2]));
        float e0 = expf(g[0] - mx), e1 = expf(g[1] - mx), e2 = expf(g[2] - mx);
        float s = e0 + e1 + e2;
        alpha[0] = e0 / s; alpha[1] = e1 / s; alpha[2] = e2 / s;
    }
    __syncthreads();
    fu[tid] = alpha[0] * a0 + alpha[1] * a1 + alpha[2] * a2;
    __syncthreads();
    float a = cb1[tid];
    for (int k = 0; k < 128; ++k) a += fu[k] * cW1[k * 128 + tid];
    h1[tid] = fmaxf(a, 0.0f);
    __syncthreads();
    if (tid < 64) {
        float b2 = cb2[tid];
        for (int k = 0; k < 128; ++k) b2 += h1[k] * cW2[k * 64 + tid];
        h2[tid] = fmaxf(b2, 0.0f);
    }
    __syncthreads();
    if (tid == 0) {
        float a3 = cb3[0];
        for (int k = 0; k < 64; ++k) a3 += h2[k] * cW3[k];
        out[b] = a3;
    }
}

extern "C" void kernel_launch(void* const* d_in, const int* in_sizes, int n_in,
                              void* d_out, int out_size, void* d_ws, size_t ws_size,
                              hipStream_t stream) {
    const float* x     = (const float*)d_in[0];
    const int*   ei0   = (const int*)d_in[1];
    const int*   ei1   = (const int*)d_in[2];
    const int*   ei2   = (const int*)d_in[3];
    const int*   batch = (const int*)d_in[4];
    const float* bn_g  = (const float*)d_in[5];
    const float* bn_b  = (const float*)d_in[6];
    const float *W[3][3], *As[3][3], *Ad[3][3], *Bi[3][3];
    for (int l = 0; l < 3; ++l) {
        const float* Wl  = (const float*)d_in[7 + 4 * l];
        const float* asl = (const float*)d_in[8 + 4 * l];
        const float* adl = (const float*)d_in[9 + 4 * l];
        const float* bl  = (const float*)d_in[10 + 4 * l];
        int fin = (l == 0) ? 128 : 64;
        for (int v = 0; v < 3; ++v) {
            W[v][l]  = Wl + (long)v * fin * HC;
            As[v][l] = asl + v * HC;
            Ad[v][l] = adl + v * HC;
            Bi[v][l] = bl + v * HC;
        }
    }
    const float* lng = (const float*)d_in[19];
    const float* lnb = (const float*)d_in[20];
    const float* pW  = (const float*)d_in[21];
    const float* pb  = (const float*)d_in[22];
    const float* gW1 = (const float*)d_in[23];
    const float* gb1 = (const float*)d_in[24];
    const float* gW2 = (const float*)d_in[25];
    const float* gb2 = (const float*)d_in[26];
    const float* cW1 = (const float*)d_in[27];
    const float* cb1 = (const float*)d_in[28];
    const float* cW2 = (const float*)d_in[29];
    const float* cb2 = (const float*)d_in[30];
    const float* cW3 = (const float*)d_in[31];
    const float* cb3 = (const float*)d_in[32];

    float* ws     = (float*)d_ws;
    float* hcat   = ws;                           // N*192
    float* h_lin  = hcat + (long)NN * 192;        // N*64
    float* s_src  = h_lin + (long)NN * HC;        // N*2
    float* s_dst  = s_src + NN * 2;               // N*2
    float* part   = s_dst + NN * 2;               // PK*B*384
    float* views  = part + (long)PK * BB * 384;   // 3*B*128
    int*   bptr   = (int*)(views + 3 * BB * 128); // B+1
    int*   deg    = bptr + BB + 1;                // 3*N
    int*   rowptr = deg + 3 * NN;                 // 3*(N+1)
    int*   cur    = rowptr + 3 * (NN + 1);        // 3*N
    int*   bsum   = cur + 3 * NN;                 // 3*256
    int*   col    = bsum + 3 * 256;               // 3*EP

    const int NB = (NN + 255) / 256;

    k_bptr<<<NB, 256, 0, stream>>>(batch, bptr);

    // ---- batched CSR build for all 3 views ----
    hipMemsetAsync(deg, 0, (size_t)3 * NN * sizeof(int), stream);
    k_hist3<<<dim3((EP + 255) / 256, 3), 256, 0, stream>>>(ei0, ei1, ei2, deg);
    k_scan1<<<dim3(NB, 3), 256, 0, stream>>>(deg, bsum);
    k_scan2<<<3, 64, 0, stream>>>(bsum, NB);
    k_scan3<<<dim3(NB, 3), 256, 0, stream>>>(deg, bsum, rowptr, cur);
    k_fill3<<<dim3((EP + 255) / 256, 3), 256, 0, stream>>>(ei0, ei1, ei2, cur, col);

    for (int v = 0; v < 3; ++v) {
        const int* rp = rowptr + (long)v * (NN + 1);
        const int* cl = col + (long)v * EP;
        for (int l = 0; l < 3; ++l) {
            float* slice = hcat + l * HC;
            if (l == 0)
                k_gemm_gat<128, 128, true, 2><<<(NN + 31) / 32, 256, 0, stream>>>(
                    x, W[v][0], As[v][0], Ad[v][0], bn_g, bn_b, h_lin, s_src, s_dst);
            else
                k_gemm_gat<64, 192, false, 4><<<(NN + 31) / 32, 256, 0, stream>>>(
                    hcat + (l - 1) * HC, W[v][l], As[v][l], Ad[v][l], bn_g, bn_b,
                    h_lin, s_src, s_dst);
            k_gat<<<(NN + 15) / 16, 256, 0, stream>>>(rp, cl, s_src, s_dst,
                                                      h_lin, Bi[v][l], slice);
        }
        k_pool<<<BB * PK, 192, 0, stream>>>(hcat, bptr, lng, lnb, part);
        k_proj<<<BB, 128, 0, stream>>>(part, bptr, pW, pb, views + (long)v * BB * 128);
    }
    k_final<<<BB, 128, 0, stream>>>(views, views + BB * 128, views + 2 * BB * 128,
                                    gW1, gb1, gW2, gb2, cW1, cb1, cW2, cb2, cW3, cb3,
                                    (float*)d_out);
}